// Round 11
// baseline (317.848 us; speedup 1.0000x reference)
//
#include <hip/hip_runtime.h>
#include <hip/hip_bf16.h>

typedef __attribute__((ext_vector_type(8))) short bf16x8;
typedef __attribute__((ext_vector_type(4))) float f32x4;
typedef unsigned short u16;

#define MFMA16(a, b, c) __builtin_amdgcn_mfma_f32_16x16x32_bf16((a), (b), (c), 0, 0, 0)
#define GLLDS(gp, lp)                                                                  \
  __builtin_amdgcn_global_load_lds((const __attribute__((address_space(1))) unsigned int*)(gp), \
                                   (__attribute__((address_space(3))) unsigned int*)(lp), 16, 0, 0)

__device__ __forceinline__ u16 f2b(float f) {
  union { float f; unsigned u; } x; x.f = f;
  return (u16)((x.u + 0x7FFFu + ((x.u >> 16) & 1u)) >> 16);  // RNE
}
__device__ __forceinline__ unsigned f2b_hw(float f) {
  union { __hip_bfloat16 h; u16 u; } c;
  c.h = __float2bfloat16(f);
  return (unsigned)c.u;
}

// ---------------- x fp32 -> bf16 ----------------
__global__ __launch_bounds__(256) void k_cvt(const float* __restrict__ in,
                                             u16* __restrict__ out, int n4) {
  int i = blockIdx.x * 256 + threadIdx.x;
  if (i >= n4) return;
  float4 v = ((const float4*)in)[i];
  u16 a = f2b(v.x), b = f2b(v.y), c = f2b(v.z), d = f2b(v.w);
  ((uint2*)out)[i] = make_uint2((unsigned)a | ((unsigned)b << 16),
                                (unsigned)c | ((unsigned)d << 16));
}

// ---------------- transpose+convert: out[C][R] = bf16(in[R][C]) ----------------
__global__ __launch_bounds__(256) void k_packT(const float* __restrict__ in,
                                               u16* __restrict__ out, int R, int C) {
  __shared__ float t[32][33];
  int r0 = blockIdx.x * 32, c0 = blockIdx.y * 32;
  int cx = threadIdx.x & 31, ry = threadIdx.x >> 5;
#pragma unroll
  for (int k = 0; k < 4; k++)
    t[ry + k * 8][cx] = in[(size_t)(r0 + ry + k * 8) * C + c0 + cx];
  __syncthreads();
#pragma unroll
  for (int k = 0; k < 4; k++)
    out[(size_t)(c0 + ry + k * 8) * R + r0 + cx] = f2b(t[cx][ry + k * 8]);
}

// ---------------- q,k projection; q linear (pre-scaled 1/8), k swizzle-tile-packed ----------------
__global__ __launch_bounds__(256) void k_gemm_qk(const u16* __restrict__ xb,
                                                 const u16* __restrict__ wqt,
                                                 const u16* __restrict__ wkt,
                                                 u16* __restrict__ q, u16* __restrict__ kk) {
  int row0 = blockIdx.x * 64;
  int tid = threadIdx.x, w = tid >> 6, l = tid & 63, l15 = l & 15, lg = l >> 4;
  const u16* wt = (w < 2) ? wqt : wkt;
  int nbase = (w & 1) * 32;
  f32x4 acc[4][2];
#pragma unroll
  for (int mt = 0; mt < 4; mt++)
#pragma unroll
    for (int nt = 0; nt < 2; nt++) acc[mt][nt] = (f32x4){0.f, 0.f, 0.f, 0.f};

  for (int k0 = 0; k0 < 1024; k0 += 32) {
    bf16x8 bfr[2], afr[4];
#pragma unroll
    for (int nt = 0; nt < 2; nt++)
      bfr[nt] = *(const bf16x8*)&wt[(size_t)(nbase + nt * 16 + l15) * 1024 + k0 + lg * 8];
#pragma unroll
    for (int mt = 0; mt < 4; mt++)
      afr[mt] = *(const bf16x8*)&xb[(size_t)(row0 + mt * 16 + l15) * 1024 + k0 + lg * 8];
#pragma unroll
    for (int mt = 0; mt < 4; mt++)
#pragma unroll
      for (int nt = 0; nt < 2; nt++) acc[mt][nt] = MFMA16(afr[mt], bfr[nt], acc[mt][nt]);
  }
  if (w < 2) {  // q: linear, scaled by 1/8
#pragma unroll
    for (int mt = 0; mt < 4; mt++)
#pragma unroll
      for (int nt = 0; nt < 2; nt++)
#pragma unroll
        for (int j = 0; j < 4; j++)
          q[(size_t)(row0 + mt * 16 + lg * 4 + j) * 64 + nbase + nt * 16 + l15] =
              f2b(acc[mt][nt][j] * 0.125f);
  } else {  // k: swizzled tile-packed
#pragma unroll
    for (int mt = 0; mt < 4; mt++)
#pragma unroll
      for (int nt = 0; nt < 2; nt++)
#pragma unroll
        for (int j = 0; j < 4; j++) {
          int row = row0 + mt * 16 + lg * 4 + j;
          int c = (nbase + nt * 16 + l15) * 2;
          size_t off = (size_t)(row >> 6) * 8192 + (row & 63) * 128 + (c ^ ((row & 7) << 4));
          *(u16*)((char*)kk + off) = f2b(acc[mt][nt][j]);
        }
  }
}

// ---------------- v projection, m97-style staged GEMM, transposed + swizzle-packed out ----------------
__global__ __launch_bounds__(256) void k_gemm_v(const u16* __restrict__ xb,
                                                const u16* __restrict__ wvt,
                                                u16* __restrict__ vT) {
  int b = blockIdx.z;
  int d0 = blockIdx.y * 128;
  int s0 = blockIdx.x * 128;
  int tid = threadIdx.x, w = tid >> 6, l = tid & 63, l15 = l & 15, lg = l >> 4;
  int wd = (w & 1) * 64, wsn = (w >> 1) * 64;
  __shared__ __align__(16) char lds[32768];

  const u16* arow = wvt + (size_t)d0 * 1024;
  const u16* brow = xb + (size_t)(b * 4096 + s0) * 1024;

  auto stage = [&](int buf, int k0) {
    char* La = lds + buf * 16384;
    char* Lb = La + 8192;
#pragma unroll
    for (int i = 0; i < 2; i++) {
      int row = w * 32 + i * 16 + (l >> 2), kq = (l & 3) * 8;
      GLLDS(&arow[(size_t)row * 1024 + k0 + kq], La + (w * 2 + i) * 1024);
      GLLDS(&brow[(size_t)row * 1024 + k0 + kq], Lb + (w * 2 + i) * 1024);
    }
  };

  f32x4 acc[4][4];
#pragma unroll
  for (int mt = 0; mt < 4; mt++)
#pragma unroll
    for (int nt = 0; nt < 4; nt++) acc[mt][nt] = (f32x4){0.f, 0.f, 0.f, 0.f};

  stage(0, 0);
  __syncthreads();
  int buf = 0;
  for (int k = 0; k < 32; k++) {
    if (k < 31) stage(buf ^ 1, (k + 1) * 32);
    const char* La = lds + buf * 16384;
    const char* Lb = La + 8192;
    bf16x8 afr[4], bfr[4];
#pragma unroll
    for (int mt = 0; mt < 4; mt++)
      afr[mt] = *(const bf16x8*)(La + (wd + mt * 16 + l15) * 64 + lg * 16);
#pragma unroll
    for (int nt = 0; nt < 4; nt++)
      bfr[nt] = *(const bf16x8*)(Lb + (wsn + nt * 16 + l15) * 64 + lg * 16);
    __builtin_amdgcn_s_setprio(1);
#pragma unroll
    for (int mt = 0; mt < 4; mt++)
#pragma unroll
      for (int nt = 0; nt < 4; nt++) acc[mt][nt] = MFMA16(afr[mt], bfr[nt], acc[mt][nt]);
    __builtin_amdgcn_s_setprio(0);
    __syncthreads();
    buf ^= 1;
  }
#pragma unroll
  for (int mt = 0; mt < 4; mt++)
#pragma unroll
    for (int nt = 0; nt < 4; nt++)
#pragma unroll
      for (int j = 0; j < 4; j++) {
        int d = d0 + wd + mt * 16 + lg * 4 + j;
        int s = s0 + wsn + nt * 16 + l15;
        size_t off = ((size_t)(b * 64 + (s >> 6)) * 8 + (d >> 7)) * 16384 + (d & 127) * 128 +
                     (((s & 63) * 2) ^ ((d & 7) << 4));
        *(u16*)((char*)vT + off) = f2b(acc[mt][nt][j]);
      }
}

// ---------------- wave-specialized flash attention ----------------
// Waves 0-3 (A): QK+softmax+P for 32 q-rows each (VALU-heavy).
// Waves 4-7 (B): PV + l for 64q x 128d each (MFMA/LDS-heavy).
// 1 A-wave + 1 B-wave per SIMD -> different pipes overlap. Window t runs
// A(t) || B(t-1); K/V/P/sc double-buffered; ONE barrier per window.
__global__ __launch_bounds__(512, 2) void k_attn(const u16* __restrict__ qw,
                                                 const u16* __restrict__ kws,
                                                 const u16* __restrict__ vts,
                                                 float* __restrict__ out) {
  int bid = blockIdx.x;
  int xcd = bid & 7, rest = bid >> 3;
  int p = rest & 15, hi = rest >> 4;
  int g = xcd + 8 * hi;  // combo id = cpair + 4*b (16 p-blocks/combo per XCD)
  int cpair = g & 3, b = g >> 2;
  int tid = threadIdx.x, w = tid >> 6, l = tid & 63, l15 = l & 15, lg = l >> 4;
  int sw = (l15 & 7) << 4;
  size_t tokb = (size_t)b * 4096;
  bool isA = w < 4;
  int wq = w & 3;                      // role-local wave index
  int qpos = wq & 1, dhalf = wq >> 1;  // B decomposition: 2 qpos x 2 dhalf

  __shared__ __align__(16) char lds[115712];
  // [0,16K)=K dbuf(8K)  [16K,80K)=V dbuf(32K)  [80K,112K)=P dbuf(16K)  sc dbuf @114688

  const short ob = (short)0x3F80;
  const bf16x8 ones = {ob, ob, ob, ob, ob, ob, ob, ob};

  auto stageV = [&](int t, int bufi) {  // 32 x 1KB slices, 4 per wave (all 8 waves)
    const char* vb = (const char*)vts + ((size_t)(b * 64 + t) * 8 + cpair * 2) * 16384;
    char* lv = lds + 16384 + bufi * 32768;
#pragma unroll
    for (int i = 0; i < 4; i++) GLLDS(vb + (w * 4 + i) * 1024 + l * 16, lv + (w * 4 + i) * 1024);
  };
  auto stageK = [&](int t, int bufi) {  // 8 x 1KB slices, 1 per wave
    const char* kb = (const char*)kws + (size_t)(b * 64 + t) * 8192;
    GLLDS(kb + w * 1024 + l * 16, lds + bufi * 8192 + w * 1024);
  };

  auto run_phase = [&](int Q0) {
    int ntb = (Q0 >> 6) + 2;
    int qsA = Q0 + wq * 32;   // A-wave q-range (32 rows)
    int qsB = Q0 + qpos * 64; // B-wave q-range (64 rows)

    bf16x8 qf[2][2];
    if (isA) {
#pragma unroll
      for (int cb = 0; cb < 2; cb++)
#pragma unroll
        for (int ks = 0; ks < 2; ks++)
          qf[cb][ks] =
              *(const bf16x8*)&qw[(tokb + qsA + cb * 16 + l15) * 64 + ks * 32 + lg * 8];
    }

    f32x4 acc[8][4], accl[4];  // B-wave state: [d-tile][q-tile]
    float mrow[2];             // A-wave state
#pragma unroll
    for (int mt = 0; mt < 8; mt++)
#pragma unroll
      for (int qt = 0; qt < 4; qt++) acc[mt][qt] = (f32x4){0.f, 0.f, 0.f, 0.f};
#pragma unroll
    for (int qt = 0; qt < 4; qt++) accl[qt] = (f32x4){0.f, 0.f, 0.f, 0.f};
    mrow[0] = mrow[1] = -1e30f;

    stageK(0, 0);
    __syncthreads();
    for (int t = 0; t <= ntb; t++) {
      if (t < ntb) stageV(t, t & 1);
      if (t + 1 < ntb) stageK(t + 1, (t + 1) & 1);
      if (isA) {
        // ---- A(t): swapped QK + softmax -> P/sc buf t&1 ----
        int s0 = t * 64;
        if (t < ntb && s0 < qsA + 32) {
          const char* Kb = lds + (t & 1) * 8192;
          char* Pw = lds + 81920 + (t & 1) * 16384;
          float* scw = (float*)(lds + 114688) + (t & 1) * 128;
          f32x4 sfr[2][4];
          __builtin_amdgcn_s_setprio(1);
#pragma unroll
          for (int nt = 0; nt < 4; nt++) {
            const char* kr = Kb + (nt * 16 + l15) * 128;
            bf16x8 kf0 = *(const bf16x8*)(kr + ((lg * 16) ^ sw));
            bf16x8 kf1 = *(const bf16x8*)(kr + ((64 + lg * 16) ^ sw));
#pragma unroll
            for (int cb = 0; cb < 2; cb++) {
              f32x4 z = (f32x4){0.f, 0.f, 0.f, 0.f};
              z = MFMA16(kf0, qf[cb][0], z);  // swapped: rows=s, cols=q
              sfr[cb][nt] = MFMA16(kf1, qf[cb][1], z);
            }
          }
          __builtin_amdgcn_s_setprio(0);
          if (s0 + 63 > qsA) {  // causal mask on diagonal-overlap tiles
#pragma unroll
            for (int cb = 0; cb < 2; cb++) {
              int qv = qsA + cb * 16 + l15;
#pragma unroll
              for (int nt = 0; nt < 4; nt++)
#pragma unroll
                for (int j = 0; j < 4; j++)
                  if (s0 + nt * 16 + lg * 4 + j > qv) sfr[cb][nt][j] = -1e30f;
            }
          }
          float pm[2];
          int need = 0;
#pragma unroll
          for (int cb = 0; cb < 2; cb++) {
            pm[cb] = fmaxf(fmaxf(fmaxf(sfr[cb][0][0], sfr[cb][0][1]),
                                 fmaxf(sfr[cb][0][2], sfr[cb][0][3])),
                           fmaxf(fmaxf(sfr[cb][1][0], sfr[cb][1][1]),
                                 fmaxf(sfr[cb][1][2], sfr[cb][1][3])));
            pm[cb] = fmaxf(pm[cb], fmaxf(fmaxf(fmaxf(sfr[cb][2][0], sfr[cb][2][1]),
                                               fmaxf(sfr[cb][2][2], sfr[cb][2][3])),
                                         fmaxf(fmaxf(sfr[cb][3][0], sfr[cb][3][1]),
                                               fmaxf(sfr[cb][3][2], sfr[cb][3][3]))));
            pm[cb] = fmaxf(pm[cb], __shfl_xor(pm[cb], 16));
            pm[cb] = fmaxf(pm[cb], __shfl_xor(pm[cb], 32));
            need |= (pm[cb] > mrow[cb] + 8.0f);
          }
          float scv[2] = {1.0f, 1.0f};
          if (__any(need)) {  // T13 defer-max
#pragma unroll
            for (int cb = 0; cb < 2; cb++) {
              float mn = fmaxf(mrow[cb], pm[cb]);
              scv[cb] = __expf(mrow[cb] - mn);
              mrow[cb] = mn;
            }
          }
#pragma unroll
          for (int cb = 0; cb < 2; cb++) {
            int rq = wq * 32 + cb * 16 + l15;
            scw[rq] = scv[cb];
            int rbase = rq * 128, sx = (rq & 7) << 4;
#pragma unroll
            for (int nt = 0; nt < 4; nt++) {
              unsigned lo = f2b_hw(__expf(sfr[cb][nt][0] - mrow[cb])) |
                            (f2b_hw(__expf(sfr[cb][nt][1] - mrow[cb])) << 16);
              unsigned hi2 = f2b_hw(__expf(sfr[cb][nt][2] - mrow[cb])) |
                             (f2b_hw(__expf(sfr[cb][nt][3] - mrow[cb])) << 16);
              int addr = (rbase + (nt * 16 + lg * 4) * 2) ^ sx;
              *(uint2*)(Pw + addr) = make_uint2(lo, hi2);
            }
          }
        }
      } else if (t >= 1) {
        // ---- B(t-1): PV + l from P/sc/V buf (t-1)&1 ----
        int tb = t - 1, s0 = tb * 64;
        int qlo = (s0 - qsB) >> 4;
        if (qlo < 0) qlo = 0;
        if (qlo < 4) {
          int bi = tb & 1;
          const char* Pb = lds + 81920 + bi * 16384;
          const float* scb = (const float*)(lds + 114688) + bi * 128;
          const char* Vb = lds + 16384 + bi * 32768 + dhalf * 16384;
          bf16x8 pf[4][2];
#pragma unroll
          for (int qt = 0; qt < 4; qt++)
            if (qt >= qlo) {
              int R = qpos * 64 + qt * 16 + l15;
              float sq = scb[R];
              if (!__all(sq == 1.0f)) {
#pragma unroll
                for (int mt = 0; mt < 8; mt++) acc[mt][qt] *= sq;
                accl[qt] *= sq;
              }
              int rx = (R & 7) << 4;
              pf[qt][0] = *(const bf16x8*)(Pb + ((R * 128 + lg * 16) ^ rx));
              pf[qt][1] = *(const bf16x8*)(Pb + ((R * 128 + 64 + lg * 16) ^ rx));
            }
          __builtin_amdgcn_s_setprio(1);
#pragma unroll
          for (int qt = 0; qt < 4; qt++)
            if (qt >= qlo) {
              accl[qt] = MFMA16(ones, pf[qt][0], accl[qt]);
              accl[qt] = MFMA16(ones, pf[qt][1], accl[qt]);
            }
#pragma unroll
          for (int mt = 0; mt < 8; mt++) {
            const char* vr = Vb + (mt * 16 + l15) * 128;
            bf16x8 va0 = *(const bf16x8*)(vr + ((lg * 16) ^ sw));
            bf16x8 va1 = *(const bf16x8*)(vr + ((64 + lg * 16) ^ sw));
#pragma unroll
            for (int qt = 0; qt < 4; qt++)
              if (qt >= qlo) {
                acc[mt][qt] = MFMA16(va0, pf[qt][0], acc[mt][qt]);
                acc[mt][qt] = MFMA16(va1, pf[qt][1], acc[mt][qt]);
              }
          }
          __builtin_amdgcn_s_setprio(0);
        }
      }
      __syncthreads();  // publish P(t), land V(t)/K(t+1)
    }
    // ---- epilogue: B-waves write out ----
    if (!isA) {
#pragma unroll
      for (int qt = 0; qt < 4; qt++) {
        float linv = 1.0f / accl[qt][0];
#pragma unroll
        for (int mt = 0; mt < 8; mt++) {
          f32x4 v = acc[mt][qt] * linv;
          size_t o = (tokb + qsB + qt * 16 + l15) * 1024 + cpair * 256 + dhalf * 128 +
                     mt * 16 + lg * 4;
          *(f32x4*)&out[o] = v;
        }
      }
    }
  };

  run_phase(p * 128);          // light q-tile
  run_phase((31 - p) * 128);   // heavy q-tile (balanced: 68 windows/block)
}

// ---------------- launch ----------------
extern "C" void kernel_launch(void* const* d_in, const int* in_sizes, int n_in,
                              void* d_out, int out_size, void* d_ws, size_t ws_size,
                              hipStream_t stream) {
  const float* x  = (const float*)d_in[0];
  const float* Wq = (const float*)d_in[1];
  const float* Wk = (const float*)d_in[2];
  const float* Wv = (const float*)d_in[3];
  float* out = (float*)d_out;
  char* ws = (char*)d_ws;
  u16* xb  = (u16*)(ws);              // 16384x1024 bf16
  u16* qw  = (u16*)(ws + 33554432);   // 16384x64 (linear)
  u16* kw  = (u16*)(ws + 35651584);   // 256 tiles x 8KB (swizzled)
  u16* vT  = (u16*)(ws + 37748736);   // 2048 tiles x 16KB (swizzled)
  u16* wqt = (u16*)(ws + 71303168);   // 64x1024
  u16* wkt = (u16*)(ws + 71434240);   // 64x1024
  u16* wvt = (u16*)(ws + 71565312);   // 1024x1024

  k_cvt<<<16384, 256, 0, stream>>>(x, xb, 4194304);
  k_packT<<<dim3(32, 2), 256, 0, stream>>>(Wq, wqt, 1024, 64);
  k_packT<<<dim3(32, 2), 256, 0, stream>>>(Wk, wkt, 1024, 64);
  k_packT<<<dim3(32, 32), 256, 0, stream>>>(Wv, wvt, 1024, 1024);
  k_gemm_qk<<<256, 256, 0, stream>>>(xb, wqt, wkt, qw, kw);
  k_gemm_v<<<dim3(32, 8, 4), 256, 0, stream>>>(xb, wvt, vT);
  k_attn<<<256, 512, 0, stream>>>(qw, kw, vT, out);
}

// Round 13
// 215.466 us; speedup vs baseline: 1.4752x; 1.4752x over previous
//
#include <hip/hip_runtime.h>
#include <hip/hip_bf16.h>

typedef __attribute__((ext_vector_type(8))) short bf16x8;
typedef __attribute__((ext_vector_type(4))) float f32x4;
typedef unsigned short u16;

#define MFMA16(a, b, c) __builtin_amdgcn_mfma_f32_16x16x32_bf16((a), (b), (c), 0, 0, 0)
#define GLLDS(gp, lp)                                                                  \
  __builtin_amdgcn_global_load_lds((const __attribute__((address_space(1))) unsigned int*)(gp), \
                                   (__attribute__((address_space(3))) unsigned int*)(lp), 16, 0, 0)

__device__ __forceinline__ float fexp2(float x) { return __builtin_amdgcn_exp2f(x); }

__device__ __forceinline__ u16 f2b(float f) {
  union { float f; unsigned u; } x; x.f = f;
  return (u16)((x.u + 0x7FFFu + ((x.u >> 16) & 1u)) >> 16);  // RNE
}
__device__ __forceinline__ unsigned f2b_hw(float f) {
  union { __hip_bfloat16 h; u16 u; } c;
  c.h = __float2bfloat16(f);
  return (unsigned)c.u;
}

// ---------------- x fp32 -> bf16 ----------------
__global__ __launch_bounds__(256) void k_cvt(const float* __restrict__ in,
                                             u16* __restrict__ out, int n4) {
  int i = blockIdx.x * 256 + threadIdx.x;
  if (i >= n4) return;
  float4 v = ((const float4*)in)[i];
  u16 a = f2b(v.x), b = f2b(v.y), c = f2b(v.z), d = f2b(v.w);
  ((uint2*)out)[i] = make_uint2((unsigned)a | ((unsigned)b << 16),
                                (unsigned)c | ((unsigned)d << 16));
}

// ---------------- transpose+convert: out[C][R] = bf16(in[R][C]) ----------------
__global__ __launch_bounds__(256) void k_packT(const float* __restrict__ in,
                                               u16* __restrict__ out, int R, int C) {
  __shared__ float t[32][33];
  int r0 = blockIdx.x * 32, c0 = blockIdx.y * 32;
  int cx = threadIdx.x & 31, ry = threadIdx.x >> 5;
#pragma unroll
  for (int k = 0; k < 4; k++)
    t[ry + k * 8][cx] = in[(size_t)(r0 + ry + k * 8) * C + c0 + cx];
  __syncthreads();
#pragma unroll
  for (int k = 0; k < 4; k++)
    out[(size_t)(c0 + ry + k * 8) * R + r0 + cx] = f2b(t[cx][ry + k * 8]);
}

// ---------------- q,k projection; q pre-scaled by (1/8)*log2(e) for exp2-domain softmax ----------------
__global__ __launch_bounds__(256) void k_gemm_qk(const u16* __restrict__ xb,
                                                 const u16* __restrict__ wqt,
                                                 const u16* __restrict__ wkt,
                                                 u16* __restrict__ q, u16* __restrict__ kk) {
  int row0 = blockIdx.x * 64;
  int tid = threadIdx.x, w = tid >> 6, l = tid & 63, l15 = l & 15, lg = l >> 4;
  const u16* wt = (w < 2) ? wqt : wkt;
  int nbase = (w & 1) * 32;
  f32x4 acc[4][2];
#pragma unroll
  for (int mt = 0; mt < 4; mt++)
#pragma unroll
    for (int nt = 0; nt < 2; nt++) acc[mt][nt] = (f32x4){0.f, 0.f, 0.f, 0.f};

  for (int k0 = 0; k0 < 1024; k0 += 32) {
    bf16x8 bfr[2], afr[4];
#pragma unroll
    for (int nt = 0; nt < 2; nt++)
      bfr[nt] = *(const bf16x8*)&wt[(size_t)(nbase + nt * 16 + l15) * 1024 + k0 + lg * 8];
#pragma unroll
    for (int mt = 0; mt < 4; mt++)
      afr[mt] = *(const bf16x8*)&xb[(size_t)(row0 + mt * 16 + l15) * 1024 + k0 + lg * 8];
#pragma unroll
    for (int mt = 0; mt < 4; mt++)
#pragma unroll
      for (int nt = 0; nt < 2; nt++) acc[mt][nt] = MFMA16(afr[mt], bfr[nt], acc[mt][nt]);
  }
  if (w < 2) {  // q: linear, scaled by (1/8)*log2e -> S' = S*log2e
#pragma unroll
    for (int mt = 0; mt < 4; mt++)
#pragma unroll
      for (int nt = 0; nt < 2; nt++)
#pragma unroll
        for (int j = 0; j < 4; j++)
          q[(size_t)(row0 + mt * 16 + lg * 4 + j) * 64 + nbase + nt * 16 + l15] =
              f2b(acc[mt][nt][j] * 0.18033688f);
  } else {  // k: swizzled tile-packed
#pragma unroll
    for (int mt = 0; mt < 4; mt++)
#pragma unroll
      for (int nt = 0; nt < 2; nt++)
#pragma unroll
        for (int j = 0; j < 4; j++) {
          int row = row0 + mt * 16 + lg * 4 + j;
          int c = (nbase + nt * 16 + l15) * 2;
          size_t off = (size_t)(row >> 6) * 8192 + (row & 63) * 128 + (c ^ ((row & 7) << 4));
          *(u16*)((char*)kk + off) = f2b(acc[mt][nt][j]);
        }
  }
}

// ---------------- v projection, m97-style staged GEMM, transposed + swizzle-packed out ----------------
__global__ __launch_bounds__(256) void k_gemm_v(const u16* __restrict__ xb,
                                                const u16* __restrict__ wvt,
                                                u16* __restrict__ vT) {
  int b = blockIdx.z;
  int d0 = blockIdx.y * 128;
  int s0 = blockIdx.x * 128;
  int tid = threadIdx.x, w = tid >> 6, l = tid & 63, l15 = l & 15, lg = l >> 4;
  int wd = (w & 1) * 64, wsn = (w >> 1) * 64;
  __shared__ __align__(16) char lds[32768];

  const u16* arow = wvt + (size_t)d0 * 1024;
  const u16* brow = xb + (size_t)(b * 4096 + s0) * 1024;

  auto stage = [&](int buf, int k0) {
    char* La = lds + buf * 16384;
    char* Lb = La + 8192;
#pragma unroll
    for (int i = 0; i < 2; i++) {
      int row = w * 32 + i * 16 + (l >> 2), kq = (l & 3) * 8;
      GLLDS(&arow[(size_t)row * 1024 + k0 + kq], La + (w * 2 + i) * 1024);
      GLLDS(&brow[(size_t)row * 1024 + k0 + kq], Lb + (w * 2 + i) * 1024);
    }
  };

  f32x4 acc[4][4];
#pragma unroll
  for (int mt = 0; mt < 4; mt++)
#pragma unroll
    for (int nt = 0; nt < 4; nt++) acc[mt][nt] = (f32x4){0.f, 0.f, 0.f, 0.f};

  stage(0, 0);
  __syncthreads();
  int buf = 0;
  for (int k = 0; k < 32; k++) {
    if (k < 31) stage(buf ^ 1, (k + 1) * 32);
    const char* La = lds + buf * 16384;
    const char* Lb = La + 8192;
    bf16x8 afr[4], bfr[4];
#pragma unroll
    for (int mt = 0; mt < 4; mt++)
      afr[mt] = *(const bf16x8*)(La + (wd + mt * 16 + l15) * 64 + lg * 16);
#pragma unroll
    for (int nt = 0; nt < 4; nt++)
      bfr[nt] = *(const bf16x8*)(Lb + (wsn + nt * 16 + l15) * 64 + lg * 16);
    __builtin_amdgcn_s_setprio(1);
#pragma unroll
    for (int mt = 0; mt < 4; mt++)
#pragma unroll
      for (int nt = 0; nt < 4; nt++) acc[mt][nt] = MFMA16(afr[mt], bfr[nt], acc[mt][nt]);
    __builtin_amdgcn_s_setprio(0);
    __syncthreads();
    buf ^= 1;
  }
#pragma unroll
  for (int mt = 0; mt < 4; mt++)
#pragma unroll
    for (int nt = 0; nt < 4; nt++)
#pragma unroll
      for (int j = 0; j < 4; j++) {
        int d = d0 + wd + mt * 16 + lg * 4 + j;
        int s = s0 + wsn + nt * 16 + l15;
        size_t off = ((size_t)(b * 64 + (s >> 6)) * 8 + (d >> 7)) * 16384 + (d & 127) * 128 +
                     (((s & 63) * 2) ^ ((d & 7) << 4));
        *(u16*)((char*)vT + off) = f2b(acc[mt][nt][j]);
      }
}

// ---------------- two-phase shared-P flash attention, 1 q-tile/block, 2 blocks/CU ----------------
// Round-9 structure (V single-buffered, 64.5KB LDS, VGPR~80). Grid 512: bids
// <256 = light q-tiles, >=256 = heavy; dispatch puts one of each on every CU
// (sum = 66 s-tiles) -> co-resident blocks overlap pipes. XCD-local combos.
__global__ __launch_bounds__(512, 2) void k_attn(const u16* __restrict__ qw,
                                                 const u16* __restrict__ kws,
                                                 const u16* __restrict__ vts,
                                                 float* __restrict__ out) {
  int bid = blockIdx.x;
  int xcd = bid & 7, r = bid >> 3;
  int cmb = r & 1, q5 = r >> 1;
  int half = q5 >> 4, idx = q5 & 15;
  int p = half ? 31 - idx : idx;   // light first, heavy second dispatch wave
  int g = xcd * 2 + cmb;           // combo: 2 per XCD (V-panel L2 locality)
  int cpair = g & 3, b = g >> 2;
  int tid = threadIdx.x, w = tid >> 6, l = tid & 63, l15 = l & 15, lg = l >> 4;
  int sw = (l15 & 7) << 4;
  size_t tokb = (size_t)b * 4096;

  __shared__ __align__(16) char lds[66048];
  // [0,16K)=K dbuf  [16K,48K)=V single  [48K,64K)=P  [64K,+512)=sc
  char* Pb = lds + 49152;
  float* scb = (float*)(lds + 65536);

  const short ob = (short)0x3F80;
  const bf16x8 ones = {ob, ob, ob, ob, ob, ob, ob, ob};
  const bf16x8 zf = {0, 0, 0, 0, 0, 0, 0, 0};

  auto stageV = [&](int t) {  // 32 x 1KB slices, 4 per wave
    const char* vb = (const char*)vts + ((size_t)(b * 64 + t) * 8 + cpair * 2) * 16384;
    char* lv = lds + 16384;
#pragma unroll
    for (int i = 0; i < 4; i++) {
      int s = w * 4 + i;
      GLLDS(vb + s * 1024 + l * 16, lv + s * 1024);
    }
  };
  auto stageK = [&](int t, int bufi) {  // 8 x 1KB slices, 1 per wave
    const char* kb = (const char*)kws + (size_t)(b * 64 + t) * 8192;
    GLLDS(kb + w * 1024 + l * 16, lds + bufi * 8192 + w * 1024);
  };

  int Q0 = p * 128;
  int ntb = (Q0 >> 6) + 2;
  int qsA = Q0 + w * 16;        // writer q-range start
  int qA = qsA + l15;           // writer's q (per lane)
  int qsB = Q0 + (w & 3) * 32;  // PV q-range start
  int dhalf = w >> 2;

  bf16x8 qf[2];
#pragma unroll
  for (int ks = 0; ks < 2; ks++)
    qf[ks] = *(const bf16x8*)&qw[(tokb + qA) * 64 + ks * 32 + lg * 8];

  f32x4 acc[8][2], accl[2];
  float mrow = -1e30f;
#pragma unroll
  for (int mt = 0; mt < 8; mt++)
#pragma unroll
    for (int qt = 0; qt < 2; qt++) acc[mt][qt] = (f32x4){0.f, 0.f, 0.f, 0.f};
  accl[0] = (f32x4){0.f, 0.f, 0.f, 0.f};
  accl[1] = (f32x4){0.f, 0.f, 0.f, 0.f};

  stageK(0, 0);
  __syncthreads();
  int buf = 0;
  for (int t = 0; t < ntb; t++) {
    int s0 = t * 64;
    stageV(t);
    if (t + 1 < ntb) stageK(t + 1, buf ^ 1);
    // ---- phase A: swapped QK + exp2-softmax + P/sc write ----
    if (s0 < qsA + 16) {
      const char* Kb = lds + buf * 8192;
      f32x4 sfr[4];
      __builtin_amdgcn_s_setprio(1);
#pragma unroll
      for (int nt = 0; nt < 4; nt++) {
        const char* kr = Kb + (nt * 16 + l15) * 128;
        bf16x8 kf0 = *(const bf16x8*)(kr + ((lg * 16) ^ sw));
        bf16x8 kf1 = *(const bf16x8*)(kr + ((64 + lg * 16) ^ sw));
        f32x4 z = (f32x4){0.f, 0.f, 0.f, 0.f};
        z = MFMA16(kf0, qf[0], z);  // swapped: rows=s, cols=q
        sfr[nt] = MFMA16(kf1, qf[1], z);
      }
      __builtin_amdgcn_s_setprio(0);
      if (s0 + 63 > qsA) {  // causal mask: s > q
#pragma unroll
        for (int nt = 0; nt < 4; nt++)
#pragma unroll
          for (int j = 0; j < 4; j++)
            if (s0 + nt * 16 + lg * 4 + j > qA) sfr[nt][j] = -1e30f;
      }
      // row-max over s: reg-local + 2 shfl
      float pm = fmaxf(fmaxf(fmaxf(sfr[0][0], sfr[0][1]), fmaxf(sfr[0][2], sfr[0][3])),
                       fmaxf(fmaxf(sfr[1][0], sfr[1][1]), fmaxf(sfr[1][2], sfr[1][3])));
      pm = fmaxf(pm, fmaxf(fmaxf(fmaxf(sfr[2][0], sfr[2][1]), fmaxf(sfr[2][2], sfr[2][3])),
                           fmaxf(fmaxf(sfr[3][0], sfr[3][1]), fmaxf(sfr[3][2], sfr[3][3]))));
      pm = fmaxf(pm, __shfl_xor(pm, 16));
      pm = fmaxf(pm, __shfl_xor(pm, 32));
      float sc = 1.0f;
      if (__any(pm > mrow + 11.54f)) {  // defer-max (8 nats in log2 domain)
        float mn = fmaxf(mrow, pm);
        sc = fexp2(mrow - mn);
        mrow = mn;
      }
      int rq = w * 16 + l15;
      scb[rq] = sc;
      int rbase = rq * 128, sx = (rq & 7) << 4;
#pragma unroll
      for (int nt = 0; nt < 4; nt++) {  // 4 s-consecutive -> one b64 write
        unsigned lo = f2b_hw(fexp2(sfr[nt][0] - mrow)) |
                      (f2b_hw(fexp2(sfr[nt][1] - mrow)) << 16);
        unsigned hi2 = f2b_hw(fexp2(sfr[nt][2] - mrow)) |
                       (f2b_hw(fexp2(sfr[nt][3] - mrow)) << 16);
        int addr = (rbase + (nt * 16 + lg * 4) * 2) ^ sx;
        *(uint2*)(Pb + addr) = make_uint2(lo, hi2);
      }
    }
    __syncthreads();  // P/sc visible; V(t) drained
    // ---- phase B: PV on 32q x 128d ----
    if (s0 < qsB + 32) {
      const char* Vb = lds + 16384 + dhalf * 16384;
      bool act0 = s0 < qsB + 16;
      int R0 = (w & 3) * 32 + l15;
      if (act0) {
        float sq0 = scb[R0];
        if (!__all(sq0 == 1.0f)) {
#pragma unroll
          for (int mt = 0; mt < 8; mt++) acc[mt][0] *= sq0;
          accl[0] *= sq0;
        }
      }
      {
        float sq1 = scb[R0 + 16];
        if (!__all(sq1 == 1.0f)) {
#pragma unroll
          for (int mt = 0; mt < 8; mt++) acc[mt][1] *= sq1;
          accl[1] *= sq1;
        }
      }
      bf16x8 pf00 = zf, pf01 = zf, pf10, pf11;
      if (act0) {
        int rx = (R0 & 7) << 4;
        pf00 = *(const bf16x8*)(Pb + ((R0 * 128 + lg * 16) ^ rx));
        pf01 = *(const bf16x8*)(Pb + ((R0 * 128 + 64 + lg * 16) ^ rx));
      }
      {
        int R1 = R0 + 16, rx = (R1 & 7) << 4;
        pf10 = *(const bf16x8*)(Pb + ((R1 * 128 + lg * 16) ^ rx));
        pf11 = *(const bf16x8*)(Pb + ((R1 * 128 + 64 + lg * 16) ^ rx));
      }
      __builtin_amdgcn_s_setprio(1);
      accl[0] = MFMA16(ones, pf00, accl[0]);
      accl[0] = MFMA16(ones, pf01, accl[0]);
      accl[1] = MFMA16(ones, pf10, accl[1]);
      accl[1] = MFMA16(ones, pf11, accl[1]);
#pragma unroll
      for (int mt = 0; mt < 8; mt++) {  // V read once, used by both qt
        const char* vr = Vb + (mt * 16 + l15) * 128;
        bf16x8 va0 = *(const bf16x8*)(vr + ((lg * 16) ^ sw));
        bf16x8 va1 = *(const bf16x8*)(vr + ((64 + lg * 16) ^ sw));
        acc[mt][0] = MFMA16(va0, pf00, acc[mt][0]);
        acc[mt][0] = MFMA16(va1, pf01, acc[mt][0]);
        acc[mt][1] = MFMA16(va0, pf10, acc[mt][1]);
        acc[mt][1] = MFMA16(va1, pf11, acc[mt][1]);
      }
      __builtin_amdgcn_s_setprio(0);
    }
    __syncthreads();  // V/P free for next tile
    buf ^= 1;
  }
  // ---- epilogue: divide by l, store O ----
#pragma unroll
  for (int qt = 0; qt < 2; qt++) {
    float linv = 1.0f / accl[qt][0];
#pragma unroll
    for (int mt = 0; mt < 8; mt++) {
      f32x4 v = acc[mt][qt] * linv;
      size_t o = (tokb + qsB + qt * 16 + l15) * 1024 + cpair * 256 + dhalf * 128 +
                 mt * 16 + lg * 4;
      *(f32x4*)&out[o] = v;
    }
  }
}

// ---------------- launch ----------------
extern "C" void kernel_launch(void* const* d_in, const int* in_sizes, int n_in,
                              void* d_out, int out_size, void* d_ws, size_t ws_size,
                              hipStream_t stream) {
  const float* x  = (const float*)d_in[0];
  const float* Wq = (const float*)d_in[1];
  const float* Wk = (const float*)d_in[2];
  const float* Wv = (const float*)d_in[3];
  float* out = (float*)d_out;
  char* ws = (char*)d_ws;
  u16* xb  = (u16*)(ws);              // 16384x1024 bf16
  u16* qw  = (u16*)(ws + 33554432);   // 16384x64 (linear, exp2-scaled)
  u16* kw  = (u16*)(ws + 35651584);   // 256 tiles x 8KB (swizzled)
  u16* vT  = (u16*)(ws + 37748736);   // 2048 tiles x 16KB (swizzled)
  u16* wqt = (u16*)(ws + 71303168);   // 64x1024
  u16* wkt = (u16*)(ws + 71434240);   // 64x1024
  u16* wvt = (u16*)(ws + 71565312);   // 1024x1024

  k_cvt<<<16384, 256, 0, stream>>>(x, xb, 4194304);
  k_packT<<<dim3(32, 2), 256, 0, stream>>>(Wq, wqt, 1024, 64);
  k_packT<<<dim3(32, 2), 256, 0, stream>>>(Wk, wkt, 1024, 64);
  k_packT<<<dim3(32, 32), 256, 0, stream>>>(Wv, wvt, 1024, 1024);
  k_gemm_qk<<<256, 256, 0, stream>>>(xb, wqt, wkt, qw, kw);
  k_gemm_v<<<dim3(32, 8, 4), 256, 0, stream>>>(xb, wvt, vT);
  k_attn<<<512, 512, 0, stream>>>(qw, kw, vT, out);
}